// Round 1
// baseline (97.104 us; speedup 1.0000x reference)
//
#include <hip/hip_runtime.h>

// Problem constants (match reference file)
#define B_ 8
#define N_ 1024
#define E_ 1536
#define FIN_ 64
#define FOUT_ 64
#define FEDGE_ 32

// Workspace layout (byte offsets, 256-aligned):
//   cnt  [E]        int    @ 0        (6144 B)
//   ends [2E]       int    @ 6144     (12288 B)
//   ew   [B*E]      float  @ 18432    (49152 B)
//   diag [B*N]      float  @ 67584    (32768 B)   -- sum of ew over incident edges
//   h    [B*N*64]   float  @ 100352   (2097152 B) -- nodes @ W
#define WS_CNT   0
#define WS_ENDS  6144
#define WS_EW    18432
#define WS_DIAG  67584
#define WS_H     100352
#define WS_ZERO_BYTES 100352   // cnt..diag must be zeroed every call (ws is poisoned)

// --- Kernel A: find the two endpoints of each edge column of inc [N,E] ---
__global__ __launch_bounds__(256) void extract_edges(const float* __restrict__ inc,
                                                     int* __restrict__ cnt,
                                                     int* __restrict__ ends) {
    int e = blockIdx.x * 256 + threadIdx.x;   // grid.x = 6 -> covers E=1536
    int i = blockIdx.y;                       // grid.y = N
    if (e >= E_) return;
    if (inc[(size_t)i * E_ + e] != 0.0f) {
        int p = atomicAdd(&cnt[e], 1);        // exactly 2 hits per edge (src != dst)
        ends[e * 2 + p] = i;
    }
}

// --- Kernel B: ew[b,e] = edges[b,e,:] . evec ; accumulate diagonal tdt ---
__global__ __launch_bounds__(256) void edge_weights(const float* __restrict__ edges,
                                                    const float* __restrict__ evec,
                                                    const int* __restrict__ ends,
                                                    float* __restrict__ ew,
                                                    float* __restrict__ diag) {
    int t = blockIdx.x * 256 + threadIdx.x;
    if (t >= B_ * E_) return;
    int b = t / E_;
    int e = t - b * E_;
    const float* ep = edges + (size_t)t * FEDGE_;
    float s = 0.0f;
#pragma unroll
    for (int f = 0; f < FEDGE_; ++f) s += ep[f] * evec[f];  // evec index wave-uniform -> scalar loads
    ew[t] = s;
    int u = ends[2 * e];
    int v = ends[2 * e + 1];
    atomicAdd(&diag[b * N_ + u], s);
    atomicAdd(&diag[b * N_ + v], s);
}

// --- Kernel C: h = nodes @ W  ([B*N,64] x [64,64]) ---
__global__ __launch_bounds__(256) void node_transform(const float* __restrict__ nodes,
                                                      const float* __restrict__ W,
                                                      float* __restrict__ h) {
    __shared__ float Wl[FIN_ * FOUT_];   // 16 KiB
    __shared__ float rows[4 * FIN_];     // 4 input rows
    int tid = threadIdx.x;
#pragma unroll
    for (int k = tid; k < FIN_ * FOUT_; k += 256) Wl[k] = W[k];
    int row0 = blockIdx.x * 4;
    rows[tid] = nodes[(size_t)row0 * FIN_ + tid];  // 256 consecutive floats = 4 rows
    __syncthreads();
    int r = tid >> 6;       // 0..3
    int f = tid & 63;       // output feature
    float acc = 0.0f;
#pragma unroll
    for (int k = 0; k < FIN_; ++k) acc += rows[r * FIN_ + k] * Wl[k * FOUT_ + f];
    h[(size_t)(row0 + r) * FOUT_ + f] = acc;
}

// --- Kernel D: per-edge scatter. One wave per (b,e); lane = feature. ---
__global__ __launch_bounds__(256) void scatter_edges(const int* __restrict__ ends,
                                                     const float* __restrict__ ew,
                                                     const float* __restrict__ lap,
                                                     const float* __restrict__ h,
                                                     float* __restrict__ out) {
    int wave = (blockIdx.x * 256 + threadIdx.x) >> 6;  // (b,e) pair index
    int lane = threadIdx.x & 63;
    if (wave >= B_ * E_) return;
    int b = wave / E_;
    int e = wave - b * E_;
    int u = ends[2 * e];
    int v = ends[2 * e + 1];
    float s = ew[wave] * lap[(size_t)u * N_ + v];  // lap symmetric
    const float* hb = h + (size_t)b * N_ * FOUT_;
    float* ob = out + (size_t)b * N_ * FOUT_;
    float hv = hb[(size_t)v * FOUT_ + lane];
    float hu = hb[(size_t)u * FOUT_ + lane];
    atomicAdd(&ob[(size_t)u * FOUT_ + lane], s * hv);
    atomicAdd(&ob[(size_t)v * FOUT_ + lane], s * hu);
}

// --- Kernel E: out[b,i,f] += diag[b,i] * lap[i,i] * h[b,i,f] ---
__global__ __launch_bounds__(256) void add_diag(const float* __restrict__ diag,
                                                const float* __restrict__ lap,
                                                const float* __restrict__ h,
                                                float* __restrict__ out) {
    int t = blockIdx.x * 256 + threadIdx.x;
    if (t >= B_ * N_ * FOUT_) return;
    int bi = t >> 6;            // b*N + i
    int i = bi & (N_ - 1);      // N = 1024 (pow2)
    out[t] += diag[bi] * lap[(size_t)i * N_ + i] * h[t];
}

extern "C" void kernel_launch(void* const* d_in, const int* in_sizes, int n_in,
                              void* d_out, int out_size, void* d_ws, size_t ws_size,
                              hipStream_t stream) {
    const float* nodes = (const float*)d_in[0];   // [B,N,64]
    const float* edges = (const float*)d_in[1];   // [B,E,32]
    const float* W     = (const float*)d_in[2];   // [64,64]
    const float* evec  = (const float*)d_in[3];   // [32]
    const float* inc   = (const float*)d_in[4];   // [N,E]
    const float* lap   = (const float*)d_in[5];   // [N,N]
    float* out = (float*)d_out;

    char* ws = (char*)d_ws;
    int*   cnt  = (int*)(ws + WS_CNT);
    int*   ends = (int*)(ws + WS_ENDS);
    float* ew   = (float*)(ws + WS_EW);
    float* diag = (float*)(ws + WS_DIAG);
    float* h    = (float*)(ws + WS_H);

    // ws and out are poisoned (0xAA) before every timed call — zero what needs zeros.
    hipMemsetAsync(ws, 0, WS_ZERO_BYTES, stream);
    hipMemsetAsync(d_out, 0, (size_t)out_size * sizeof(float), stream);

    extract_edges<<<dim3((E_ + 255) / 256, N_), 256, 0, stream>>>(inc, cnt, ends);
    node_transform<<<(B_ * N_) / 4, 256, 0, stream>>>(nodes, W, h);
    edge_weights<<<(B_ * E_ + 255) / 256, 256, 0, stream>>>(edges, evec, ends, ew, diag);
    scatter_edges<<<(B_ * E_ * 64) / 256, 256, 0, stream>>>(ends, ew, lap, h, out);
    add_diag<<<(B_ * N_ * FOUT_) / 256, 256, 0, stream>>>(diag, lap, h, out);
}

// Round 2
// 85.358 us; speedup vs baseline: 1.1376x; 1.1376x over previous
//
#include <hip/hip_runtime.h>

// Problem constants (match reference file)
#define B_ 8
#define N_ 1024
#define E_ 1536
#define FIN_ 64
#define FOUT_ 64
#define FEDGE_ 32

// Workspace layout (byte offsets):
//   ends_lo [E]      uint   @ 0        (6144 B)  -- min endpoint per edge (unsigned atomicMin)
//   ends_hi [E]      int    @ 6144     (6144 B)  -- max endpoint per edge (signed atomicMax)
//   ew      [B*E]    float  @ 12288    (49152 B) -- edges . edge_weight_vec
//   h       [B*N*64] float  @ 61440    (2 MiB)   -- nodes @ W
#define WS_LO   0
#define WS_HI   6144
#define WS_EW   12288
#define WS_H    61440

// Fused kernel 1 block-range split (all parts independent):
//   [0, 2048)        : node transform (4 rows/block) + zero out
//   [2048, 3584)     : incidence scan -> edge endpoints (float4, init-free via 0xAA sentinels)
//   [3584, 3632)     : edge weight dot products
#define NT_BLOCKS 2048
#define EX_BLOCKS 1536
#define EW_BLOCKS 48
#define K1_BLOCKS (NT_BLOCKS + EX_BLOCKS + EW_BLOCKS)

__global__ __launch_bounds__(256) void fused_prep(
    const float* __restrict__ nodes,   // [B*N, 64]
    const float* __restrict__ W,       // [64, 64]
    const float* __restrict__ inc,     // [N, E]
    const float* __restrict__ edges,   // [B*E, 32]
    const float* __restrict__ evec,    // [32]
    unsigned*    __restrict__ ends_lo, // [E] pre-filled 0xAAAAAAAA
    int*         __restrict__ ends_hi, // [E] pre-filled 0xAAAAAAAA
    float*       __restrict__ ew,      // [B*E]
    float*       __restrict__ h,       // [B*N, 64]
    float*       __restrict__ out)     // [B*N, 64] -- zeroed here
{
    __shared__ float Wl[FIN_ * FOUT_];   // 16 KiB
    __shared__ float rows[4 * FIN_];     // 1 KiB
    const int blk = blockIdx.x;
    const int tid = threadIdx.x;

    if (blk < NT_BLOCKS) {
        // ---- h = nodes @ W ; out = 0 ----
#pragma unroll
        for (int k = tid; k < FIN_ * FOUT_; k += 256) Wl[k] = W[k];
        const int row0 = blk * 4;
        rows[tid] = nodes[(size_t)row0 * FIN_ + tid];  // 256 consecutive floats = 4 rows
        __syncthreads();
        const int r = tid >> 6;
        const int f = tid & 63;
        float acc = 0.0f;
#pragma unroll
        for (int k = 0; k < FIN_; ++k) acc += rows[r * FIN_ + k] * Wl[k * FOUT_ + f];
        const size_t o = (size_t)(row0 + r) * FOUT_ + f;
        h[o] = acc;
        out[o] = 0.0f;
    } else if (blk < NT_BLOCKS + EX_BLOCKS) {
        // ---- incidence scan: inc is [N,E] row-major; flat float4 index g ----
        const int g = (blk - NT_BLOCKS) * 256 + tid;   // [0, N*E/4)
        const int row = g / (E_ / 4);                  // node index
        const int q = g - row * (E_ / 4);
        const float4 c = ((const float4*)inc)[g];
        const int e0 = q * 4;
        if (c.x != 0.0f) { atomicMin(&ends_lo[e0 + 0], (unsigned)row); atomicMax(&ends_hi[e0 + 0], row); }
        if (c.y != 0.0f) { atomicMin(&ends_lo[e0 + 1], (unsigned)row); atomicMax(&ends_hi[e0 + 1], row); }
        if (c.z != 0.0f) { atomicMin(&ends_lo[e0 + 2], (unsigned)row); atomicMax(&ends_hi[e0 + 2], row); }
        if (c.w != 0.0f) { atomicMin(&ends_lo[e0 + 3], (unsigned)row); atomicMax(&ends_hi[e0 + 3], row); }
    } else {
        // ---- ew[b,e] = edges[b,e,:] . evec ----
        const int t = (blk - NT_BLOCKS - EX_BLOCKS) * 256 + tid;  // [0, B*E)
        const float4* ep = (const float4*)(edges + (size_t)t * FEDGE_);
        float s = 0.0f;
#pragma unroll
        for (int j = 0; j < FEDGE_ / 4; ++j) {
            const float4 a = ep[j];
            s += a.x * evec[4 * j + 0] + a.y * evec[4 * j + 1]
               + a.z * evec[4 * j + 2] + a.w * evec[4 * j + 3];
        }
        ew[t] = s;
    }
}

// ---- Kernel 2: per-edge scatter (off-diagonal + both diagonal contributions) ----
// out[b,u,:] += ew*(lap[u,v]*h[b,v,:] + lap[u,u]*h[b,u,:])
// out[b,v,:] += ew*(lap[u,v]*h[b,u,:] + lap[v,v]*h[b,v,:])
__global__ __launch_bounds__(256) void scatter_edges(
    const unsigned* __restrict__ ends_lo,
    const int*      __restrict__ ends_hi,
    const float*    __restrict__ ew,
    const float*    __restrict__ lap,   // [N,N]
    const float*    __restrict__ h,     // [B*N,64]
    float*          __restrict__ out)   // [B*N,64]
{
    const int wid = (blockIdx.x * 256 + threadIdx.x) >> 6;  // (b,e) pair
    const int lane = threadIdx.x & 63;
    if (wid >= B_ * E_) return;
    const int b = wid / E_;
    const int e = wid - b * E_;
    const int u = (int)ends_lo[e];
    const int v = ends_hi[e];
    const float s = ew[wid];
    const float* lrow = lap + (size_t)u * N_;
    const float luv = lrow[v];
    const float luu = lrow[u];
    const float lvv = lap[(size_t)v * N_ + v];
    const float* hb = h + (size_t)b * N_ * FOUT_;
    float* ob = out + (size_t)b * N_ * FOUT_;
    const float hu = hb[(size_t)u * FOUT_ + lane];
    const float hv = hb[(size_t)v * FOUT_ + lane];
    atomicAdd(&ob[(size_t)u * FOUT_ + lane], s * (luv * hv + luu * hu));
    atomicAdd(&ob[(size_t)v * FOUT_ + lane], s * (luv * hu + lvv * hv));
}

extern "C" void kernel_launch(void* const* d_in, const int* in_sizes, int n_in,
                              void* d_out, int out_size, void* d_ws, size_t ws_size,
                              hipStream_t stream) {
    const float* nodes = (const float*)d_in[0];   // [B,N,64]
    const float* edges = (const float*)d_in[1];   // [B,E,32]
    const float* W     = (const float*)d_in[2];   // [64,64]
    const float* evec  = (const float*)d_in[3];   // [32]
    const float* inc   = (const float*)d_in[4];   // [N,E]
    const float* lap   = (const float*)d_in[5];   // [N,N]
    float* out = (float*)d_out;

    char* ws = (char*)d_ws;
    unsigned* ends_lo = (unsigned*)(ws + WS_LO);
    int*      ends_hi = (int*)(ws + WS_HI);
    float*    ew      = (float*)(ws + WS_EW);
    float*    h       = (float*)(ws + WS_H);

    // 0xAA sentinels: ends_lo = 2.86e9 (> any node id, valid for unsigned min),
    // ends_hi = -1.43e9 (< 0, valid for signed max). 12 KiB fill — self-contained,
    // does not rely on harness poison reaching the first call.
    hipMemsetAsync(ws, 0xAA, 2 * E_ * sizeof(int), stream);

    fused_prep<<<K1_BLOCKS, 256, 0, stream>>>(nodes, W, inc, edges, evec,
                                              ends_lo, ends_hi, ew, h, out);
    scatter_edges<<<(B_ * E_ * 64) / 256, 256, 0, stream>>>(ends_lo, ends_hi, ew, lap, h, out);
}